// Round 10
// baseline (272.042 us; speedup 1.0000x reference)
//
#include <hip/hip_runtime.h>
#include <hip/hip_bf16.h>

typedef unsigned short u16;
typedef __attribute__((ext_vector_type(8))) short bf16x8;   // 8 bf16 (4 VGPRs)
typedef __attribute__((ext_vector_type(4))) float f32x4;

#define Bdim 4
#define Nseq 2048
#define DIMc 1024
#define NH   16
#define HD   64
#define F3   3072   // 3*NH*HD
#define Mrows 8192  // Bdim*Nseq

#define KPAD 68     // LDS row stride in u16: 136 B -> 2-way banks (free); r9: conflicts 7.4e6->1.6e6

typedef const __attribute__((address_space(1))) unsigned int gl_u32;
typedef __attribute__((address_space(3))) unsigned int lds_u32;

// f32 -> bf16 RNE
static __device__ __forceinline__ u16 f2b(float f) {
    union { float f; unsigned u; } v; v.f = f;
    unsigned r = v.u + 0x7fffu + ((v.u >> 16) & 1u);
    return (u16)(r >> 16);
}

__global__ __launch_bounds__(256) void cast_f32_bf16_kernel(const float* __restrict__ in,
                                                            u16* __restrict__ out, int n4) {
    int i = blockIdx.x * 256 + threadIdx.x;
    if (i >= n4) return;
    float4 v = reinterpret_cast<const float4*>(in)[i];
    ushort4 o;
    o.x = f2b(v.x); o.y = f2b(v.y); o.z = f2b(v.z); o.w = f2b(v.w);
    reinterpret_cast<ushort4*>(out)[i] = o;
}

// Normalize a 0/1 mask buffer of unknown dtype (int32 / float32 / uint8) to int32.
__global__ __launch_bounds__(256) void norm_mask_kernel(const void* __restrict__ raw, int n,
                                                        int* __restrict__ outm) {
    const unsigned* as_u = (const unsigned*)raw;
    const float* as_f = (const float*)raw;
    const unsigned char* as_b = (const unsigned char*)raw;
    int ns = n < 512 ? n : 512;
    bool ok_i = true, ok_f = true;
    for (int i = 0; i < ns; ++i) {
        unsigned v = as_u[i];
        ok_i &= (v <= 1u);
        ok_f &= (v == 0u) || (v == 0x3f800000u);
    }
    const int mode = ok_i ? 0 : (ok_f ? 1 : 2);
    int i = blockIdx.x * 256 + threadIdx.x;
    if (i < n) {
        int v;
        if (mode == 0) v = (int)as_u[i];
        else if (mode == 1) v = (as_f[i] != 0.f) ? 1 : 0;
        else v = (int)as_b[i];
        outm[i] = (v != 0) ? 1 : 0;
    }
}

// ===== MFMA QKV GEMM, m97-style: global_load_lds w16, linear LDS, BK=32 =====
__global__ __launch_bounds__(256, 2) void qkv_gemm_kernel(const u16* __restrict__ A,
                                                          const u16* __restrict__ Bw,
                                                          u16* __restrict__ C) {
    __shared__ u16 As[128 * 32];
    __shared__ u16 Bs[128 * 32];
    const int t = threadIdx.x;
    const int lane = t & 63;
    const int wave = t >> 6;
    const int wr = (wave >> 1) * 64;
    const int wc = (wave & 1) * 64;
    const int row0 = blockIdx.x * 128;
    const int col0 = blockIdx.y * 128;

    const int lr = lane & 15;
    const int lk = (lane >> 4) * 8;
    const int cr = (lane >> 4) * 4;
    const int cc = lane & 15;

    const f32x4 fzero = {0.f, 0.f, 0.f, 0.f};
    f32x4 acc[4][4];
#pragma unroll
    for (int i = 0; i < 4; ++i)
#pragma unroll
        for (int j = 0; j < 4; ++j) acc[i][j] = fzero;

    const int strow = wave * 16 + (lane >> 2);
    const int stcol = (lane & 3) * 8;

    for (int k0 = 0; k0 < DIMc; k0 += 32) {
        __syncthreads();
#pragma unroll
        for (int issue = 0; issue < 2; ++issue) {
            const int r = issue * 64 + strow;
            __builtin_amdgcn_global_load_lds(
                (gl_u32*)(A + (size_t)(row0 + r) * DIMc + k0 + stcol),
                (lds_u32*)(As + (size_t)(issue * 64 + wave * 16) * 32), 16, 0, 0);
            __builtin_amdgcn_global_load_lds(
                (gl_u32*)(Bw + (size_t)(col0 + r) * DIMc + k0 + stcol),
                (lds_u32*)(Bs + (size_t)(issue * 64 + wave * 16) * 32), 16, 0, 0);
        }
        __syncthreads();

        bf16x8 af[4], bfr[4];
#pragma unroll
        for (int i = 0; i < 4; ++i) {
            af[i]  = *reinterpret_cast<const bf16x8*>(&As[(wr + i * 16 + lr) * 32 + lk]);
            bfr[i] = *reinterpret_cast<const bf16x8*>(&Bs[(wc + i * 16 + lr) * 32 + lk]);
        }
#pragma unroll
        for (int mi = 0; mi < 4; ++mi)
#pragma unroll
            for (int ni = 0; ni < 4; ++ni)
                acc[mi][ni] = __builtin_amdgcn_mfma_f32_16x16x32_bf16(af[mi], bfr[ni], acc[mi][ni], 0, 0, 0);
    }

#pragma unroll
    for (int mi = 0; mi < 4; ++mi)
#pragma unroll
        for (int ni = 0; ni < 4; ++ni)
#pragma unroll
            for (int j = 0; j < 4; ++j) {
                int r = row0 + wr + mi * 16 + cr + j;
                int c = col0 + wc + ni * 16 + cc;
                C[(size_t)r * F3 + c] = f2b(acc[mi][ni][j]);
            }
}

// ===== per-32-row-tile attention compute (2 q-frags), bias masking =====
static __device__ __forceinline__ void attn_tile_compute(
    const bf16x8 (&qfr)[2][2],
    float (&mrow)[2], float (&lsum)[2], f32x4 (&oacc)[4][2],
    const bf16x8 (&ka)[4][2], const bf16x8 (&va)[4][2],
    const float (&fb)[4][4],
    int wq0, int m0, bool needCausal,
    u16 (*Psw)[KPAD], int g, int lq)
{
    const f32x4 fzero = {0.f, 0.f, 0.f, 0.f};
    // S^T = K Q^T : lane holds q = lq, k = kf*16 + g*4 + r
    f32x4 sacc[4][2];
#pragma unroll
    for (int kf = 0; kf < 4; ++kf)
#pragma unroll
        for (int qf = 0; qf < 2; ++qf) sacc[kf][qf] = fzero;
#pragma unroll
    for (int kf = 0; kf < 4; ++kf)
#pragma unroll
        for (int qf = 0; qf < 2; ++qf) {
            sacc[kf][qf] = __builtin_amdgcn_mfma_f32_16x16x32_bf16(ka[kf][0], qfr[qf][0], sacc[kf][qf], 0, 0, 0);
            sacc[kf][qf] = __builtin_amdgcn_mfma_f32_16x16x32_bf16(ka[kf][1], qfr[qf][1], sacc[kf][qf], 0, 0, 0);
        }

#pragma unroll
    for (int qf = 0; qf < 2; ++qf) {
        const int qg = wq0 + qf * 16 + lq;
        float s[4][4];
        float mx = -1e30f;
#pragma unroll
        for (int kf = 0; kf < 4; ++kf)
#pragma unroll
            for (int r = 0; r < 4; ++r) {
                float sv = fmaf(sacc[kf][qf][r], 0.125f, fb[kf][r]);   // 1/sqrt(64) + key-mask bias
                if (needCausal) {
                    const int kg = m0 + kf * 16 + g * 4 + r;
                    sv = (kg <= qg) ? sv : -1e30f;
                }
                s[kf][r] = sv;
                mx = fmaxf(mx, sv);
            }
        mx = fmaxf(mx, __shfl_xor(mx, 16));
        mx = fmaxf(mx, __shfl_xor(mx, 32));
        const float mnew = fmaxf(mrow[qf], mx);
        const float scale = __expf(mrow[qf] - mnew);
        float rs = 0.f;
#pragma unroll
        for (int kf = 0; kf < 4; ++kf)
#pragma unroll
            for (int r = 0; r < 4; ++r) {
                // unguarded: masked elems underflow to 0; all-masked-tile garbage (exp(0)=1)
                // is flushed by the next rescale (scale=exp(-1e30-m)=0); fully-masked rows
                // are zeroed at the epilogue via the mrow sentinel.
                const float pv = __expf(s[kf][r] - mnew);
                s[kf][r] = pv;
                rs += pv;
            }
        rs += __shfl_xor(rs, 16);
        rs += __shfl_xor(rs, 32);
        lsum[qf] = lsum[qf] * scale + rs;
        mrow[qf] = mnew;
#pragma unroll
        for (int df = 0; df < 4; ++df) oacc[df][qf] *= scale;
#pragma unroll
        for (int kf = 0; kf < 4; ++kf)
#pragma unroll
            for (int r = 0; r < 4; ++r)
                Psw[qf * 16 + lq][kf * 16 + g * 4 + r] = f2b(s[kf][r]);
    }

    // O^T += V^T P^T (Psw wave-local)
    bf16x8 pb[2][2];
#pragma unroll
    for (int qf = 0; qf < 2; ++qf)
#pragma unroll
        for (int kc = 0; kc < 2; ++kc)
            pb[qf][kc] = *reinterpret_cast<const bf16x8*>(&Psw[qf * 16 + lq][kc * 32 + g * 8]);
#pragma unroll
    for (int df = 0; df < 4; ++df)
#pragma unroll
        for (int qf = 0; qf < 2; ++qf) {
            oacc[df][qf] = __builtin_amdgcn_mfma_f32_16x16x32_bf16(va[df][0], pb[qf][0], oacc[df][qf], 0, 0, 0);
            oacc[df][qf] = __builtin_amdgcn_mfma_f32_16x16x32_bf16(va[df][1], pb[qf][1], oacc[df][qf], 0, 0, 0);
        }
}

// ===== MFMA flash attention: paired 128-row q-tiles (p, 15-p) =====
// Block = (b, h, pair p in 0..7). 4 waves x 32 q-rows per tile. Output f32.
// NOTE: (256,2) — (256,4) forced VGPR=64 and catastrophic spills (r8).
__global__ __launch_bounds__(256, 2) void attn_kernel(const u16* __restrict__ qkv,
                                                      const int* __restrict__ key_mask,
                                                      const int* __restrict__ query_mask,
                                                      const int* __restrict__ causal_p,
                                                      float* __restrict__ out) {
    const int bh = blockIdx.x;
    const int p = blockIdx.y;           // 0..7
    const int b = bh >> 4;
    const int h = bh & 15;
    const int t = threadIdx.x;
    const int lane = t & 63;
    const int wave = t >> 6;
    const int g = lane >> 4;
    const int lq = lane & 15;
    const int causal = causal_p[0];

    __shared__ u16 Ks[64][KPAD];
    __shared__ u16 Vt[64][KPAD];
    __shared__ u16 Ps[4][32][KPAD];

    const int q0A = p * 128;
    const int q0B = (15 - p) * 128;
    const int wq0A = q0A + wave * 32;
    const int wq0B = q0B + wave * 32;

    const f32x4 fzero = {0.f, 0.f, 0.f, 0.f};

    bf16x8 qfrA[2][2], qfrB[2][2];
#pragma unroll
    for (int qf = 0; qf < 2; ++qf)
#pragma unroll
        for (int ks = 0; ks < 2; ++ks) {
            qfrA[qf][ks] = *reinterpret_cast<const bf16x8*>(
                qkv + (size_t)(b * Nseq + wq0A + qf * 16 + lq) * F3 + h * HD + ks * 32 + g * 8);
            qfrB[qf][ks] = *reinterpret_cast<const bf16x8*>(
                qkv + (size_t)(b * Nseq + wq0B + qf * 16 + lq) * F3 + h * HD + ks * 32 + g * 8);
        }

    int qmA[2], qmB[2];
    float mrowA[2], lsumA[2], mrowB[2], lsumB[2];
    f32x4 oaccA[4][2], oaccB[4][2];
#pragma unroll
    for (int qf = 0; qf < 2; ++qf) {
        qmA[qf] = query_mask[b * Nseq + wq0A + qf * 16 + lq];
        qmB[qf] = query_mask[b * Nseq + wq0B + qf * 16 + lq];
        mrowA[qf] = -1e30f; lsumA[qf] = 0.f;
        mrowB[qf] = -1e30f; lsumB[qf] = 0.f;
    }
#pragma unroll
    for (int df = 0; df < 4; ++df)
#pragma unroll
        for (int qf = 0; qf < 2; ++qf) { oaccA[df][qf] = fzero; oaccB[df][qf] = fzero; }

    const int kvendA = causal ? (q0A + 128) : Nseq;
    const int kvendB = causal ? (q0B + 128) : Nseq;   // >= kvendA

    const int sr = t >> 2;
    const int sc = (t & 3) * 8;

    // prologue: load K/V for m0 = 0
    bf16x8 kr0, kr1, vr0, vr1;
    {
        const u16* krow = qkv + (size_t)(b * Nseq + sr) * F3 + DIMc + h * HD;
        kr0 = *reinterpret_cast<const bf16x8*>(krow + sc);
        kr1 = *reinterpret_cast<const bf16x8*>(krow + sc + 32);
        const u16* vrow = qkv + (size_t)(b * Nseq + lane) * F3 + 2 * DIMc + h * HD + wave * 16;
        vr0 = *reinterpret_cast<const bf16x8*>(vrow);
        vr1 = *reinterpret_cast<const bf16x8*>(vrow + 8);
    }

    for (int m0 = 0; m0 < kvendB; m0 += 64) {
        // ---- write staged regs -> LDS ----
        *reinterpret_cast<bf16x8*>(&Ks[sr][sc])      = kr0;
        *reinterpret_cast<bf16x8*>(&Ks[sr][sc + 32]) = kr1;
#pragma unroll
        for (int e = 0; e < 8; ++e) {
            Vt[wave * 16 + e][lane]     = (u16)vr0[e];
            Vt[wave * 16 + 8 + e][lane] = (u16)vr1[e];
        }
        __syncthreads();

        // ---- prefetch next tile into registers ----
        if (m0 + 64 < kvendB) {
            const u16* krow = qkv + (size_t)(b * Nseq + m0 + 64 + sr) * F3 + DIMc + h * HD;
            kr0 = *reinterpret_cast<const bf16x8*>(krow + sc);
            kr1 = *reinterpret_cast<const bf16x8*>(krow + sc + 32);
            const u16* vrow = qkv + (size_t)(b * Nseq + m0 + 64 + lane) * F3 + 2 * DIMc + h * HD + wave * 16;
            vr0 = *reinterpret_cast<const bf16x8*>(vrow);
            vr1 = *reinterpret_cast<const bf16x8*>(vrow + 8);
        }

        // ---- key-mask additive bias, shared by both tiles (and all 4 units) ----
        float fb[4][4];
#pragma unroll
        for (int kf = 0; kf < 4; ++kf) {
            int4 k4 = *reinterpret_cast<const int4*>(key_mask + b * Nseq + m0 + kf * 16 + g * 4);
            fb[kf][0] = k4.x ? 0.f : -1e30f;
            fb[kf][1] = k4.y ? 0.f : -1e30f;
            fb[kf][2] = k4.z ? 0.f : -1e30f;
            fb[kf][3] = k4.w ? 0.f : -1e30f;
        }
        bf16x8 ka[4][2], va[4][2];
#pragma unroll
        for (int kf = 0; kf < 4; ++kf)
#pragma unroll
            for (int ks = 0; ks < 2; ++ks)
                ka[kf][ks] = *reinterpret_cast<const bf16x8*>(&Ks[kf * 16 + lq][ks * 32 + g * 8]);
#pragma unroll
        for (int df = 0; df < 4; ++df)
#pragma unroll
            for (int kc = 0; kc < 2; ++kc)
                va[df][kc] = *reinterpret_cast<const bf16x8*>(&Vt[df * 16 + lq][kc * 32 + g * 8]);

        const bool ncB = causal && (m0 + 64 > q0B);
        const bool ncA = causal && (m0 + 64 > q0A);

        attn_tile_compute(qfrB, mrowB, lsumB, oaccB, ka, va, fb, wq0B, m0, ncB, Ps[wave], g, lq);
        if (m0 < kvendA)
            attn_tile_compute(qfrA, mrowA, lsumA, oaccA, ka, va, fb, wq0A, m0, ncA, Ps[wave], g, lq);
        __syncthreads();
    }

    // ---- epilogue: normalize; masked / fully-masked rows -> 0 ----
#pragma unroll
    for (int qf = 0; qf < 2; ++qf) {
        const float invA = (qmA[qf] != 0 && mrowA[qf] > -1e29f && lsumA[qf] > 0.f) ? 1.f / lsumA[qf] : 0.f;
        const float invB = (qmB[qf] != 0 && mrowB[qf] > -1e29f && lsumB[qf] > 0.f) ? 1.f / lsumB[qf] : 0.f;
        const size_t rowA = (size_t)(b * Nseq + wq0A + qf * 16 + lq) * DIMc + h * HD;
        const size_t rowB = (size_t)(b * Nseq + wq0B + qf * 16 + lq) * DIMc + h * HD;
#pragma unroll
        for (int df = 0; df < 4; ++df)
#pragma unroll
            for (int r = 0; r < 4; ++r) {
                out[rowA + df * 16 + g * 4 + r] = oaccA[df][qf][r] * invA;
                out[rowB + df * 16 + g * 4 + r] = oaccB[df][qf][r] * invB;
            }
    }
}

extern "C" void kernel_launch(void* const* d_in, const int* in_sizes, int n_in,
                              void* d_out, int out_size, void* d_ws, size_t ws_size,
                              hipStream_t stream) {
    const float* x = (const float*)d_in[0];       // [4,2048,1024] f32
    const float* W = (const float*)d_in[1];       // [3072,1024] f32

    char* ws = (char*)d_ws;
    int* km_n = (int*)(ws);
    int* qm_n = (int*)(ws + 32 * 1024);
    int* ca_n = (int*)(ws + 64 * 1024);
    u16* qkv  = (u16*)(ws + (size_t)1024 * 1024);             // 48 MiB
    u16* xb   = (u16*)(ws + (size_t)49 * 1024 * 1024);        // 16 MiB
    u16* wb   = (u16*)(ws + (size_t)65 * 1024 * 1024);        //  6 MiB

    const int nm = Bdim * Nseq;
    norm_mask_kernel<<<(nm + 255) / 256, 256, 0, stream>>>(d_in[2], nm, km_n);
    norm_mask_kernel<<<(nm + 255) / 256, 256, 0, stream>>>(d_in[3], nm, qm_n);
    norm_mask_kernel<<<1, 256, 0, stream>>>(d_in[4], 1, ca_n);

    const int nx4 = (Mrows * DIMc) / 4;
    const int nw4 = (F3 * DIMc) / 4;
    cast_f32_bf16_kernel<<<(nx4 + 255) / 256, 256, 0, stream>>>(x, xb, nx4);
    cast_f32_bf16_kernel<<<(nw4 + 255) / 256, 256, 0, stream>>>(W, wb, nw4);

    qkv_gemm_kernel<<<dim3(Mrows / 128, F3 / 128), 256, 0, stream>>>(xb, wb, qkv);

    attn_kernel<<<dim3(Bdim * NH, 8), 256, 0, stream>>>(qkv, km_n, qm_n, ca_n,
                                                        (float*)d_out);
}

// Round 11
// 269.628 us; speedup vs baseline: 1.0090x; 1.0090x over previous
//
#include <hip/hip_runtime.h>
#include <hip/hip_bf16.h>

typedef unsigned short u16;
typedef __attribute__((ext_vector_type(8))) short bf16x8;   // 8 bf16 (4 VGPRs)
typedef __attribute__((ext_vector_type(4))) float f32x4;

#define Bdim 4
#define Nseq 2048
#define DIMc 1024
#define NH   16
#define HD   64
#define F3   3072   // 3*NH*HD
#define Mrows 8192  // Bdim*Nseq

#define KPAD 68     // LDS row stride in u16: 136 B -> low bank aliasing (r9/r10 verified)

typedef const __attribute__((address_space(1))) unsigned int gl_u32;
typedef __attribute__((address_space(3))) unsigned int lds_u32;

// f32 -> bf16 RNE
static __device__ __forceinline__ u16 f2b(float f) {
    union { float f; unsigned u; } v; v.f = f;
    unsigned r = v.u + 0x7fffu + ((v.u >> 16) & 1u);
    return (u16)(r >> 16);
}

__global__ __launch_bounds__(256) void cast_f32_bf16_kernel(const float* __restrict__ in,
                                                            u16* __restrict__ out, int n4) {
    int i = blockIdx.x * 256 + threadIdx.x;
    if (i >= n4) return;
    float4 v = reinterpret_cast<const float4*>(in)[i];
    ushort4 o;
    o.x = f2b(v.x); o.y = f2b(v.y); o.z = f2b(v.z); o.w = f2b(v.w);
    reinterpret_cast<ushort4*>(out)[i] = o;
}

// Normalize a 0/1 mask buffer of unknown dtype (int32 / float32 / uint8) to int32.
__global__ __launch_bounds__(256) void norm_mask_kernel(const void* __restrict__ raw, int n,
                                                        int* __restrict__ outm) {
    const unsigned* as_u = (const unsigned*)raw;
    const float* as_f = (const float*)raw;
    const unsigned char* as_b = (const unsigned char*)raw;
    int ns = n < 512 ? n : 512;
    bool ok_i = true, ok_f = true;
    for (int i = 0; i < ns; ++i) {
        unsigned v = as_u[i];
        ok_i &= (v <= 1u);
        ok_f &= (v == 0u) || (v == 0x3f800000u);
    }
    const int mode = ok_i ? 0 : (ok_f ? 1 : 2);
    int i = blockIdx.x * 256 + threadIdx.x;
    if (i < n) {
        int v;
        if (mode == 0) v = (int)as_u[i];
        else if (mode == 1) v = (as_f[i] != 0.f) ? 1 : 0;
        else v = (int)as_b[i];
        outm[i] = (v != 0) ? 1 : 0;
    }
}

// ===== MFMA QKV GEMM, m97-style: global_load_lds w16, linear LDS, BK=32 =====
__global__ __launch_bounds__(256, 2) void qkv_gemm_kernel(const u16* __restrict__ A,
                                                          const u16* __restrict__ Bw,
                                                          u16* __restrict__ C) {
    __shared__ u16 As[128 * 32];
    __shared__ u16 Bs[128 * 32];
    const int t = threadIdx.x;
    const int lane = t & 63;
    const int wave = t >> 6;
    const int wr = (wave >> 1) * 64;
    const int wc = (wave & 1) * 64;
    const int row0 = blockIdx.x * 128;
    const int col0 = blockIdx.y * 128;

    const int lr = lane & 15;
    const int lk = (lane >> 4) * 8;
    const int cr = (lane >> 4) * 4;
    const int cc = lane & 15;

    const f32x4 fzero = {0.f, 0.f, 0.f, 0.f};
    f32x4 acc[4][4];
#pragma unroll
    for (int i = 0; i < 4; ++i)
#pragma unroll
        for (int j = 0; j < 4; ++j) acc[i][j] = fzero;

    const int strow = wave * 16 + (lane >> 2);
    const int stcol = (lane & 3) * 8;

    for (int k0 = 0; k0 < DIMc; k0 += 32) {
        __syncthreads();
#pragma unroll
        for (int issue = 0; issue < 2; ++issue) {
            const int r = issue * 64 + strow;
            __builtin_amdgcn_global_load_lds(
                (gl_u32*)(A + (size_t)(row0 + r) * DIMc + k0 + stcol),
                (lds_u32*)(As + (size_t)(issue * 64 + wave * 16) * 32), 16, 0, 0);
            __builtin_amdgcn_global_load_lds(
                (gl_u32*)(Bw + (size_t)(col0 + r) * DIMc + k0 + stcol),
                (lds_u32*)(Bs + (size_t)(issue * 64 + wave * 16) * 32), 16, 0, 0);
        }
        __syncthreads();

        bf16x8 af[4], bfr[4];
#pragma unroll
        for (int i = 0; i < 4; ++i) {
            af[i]  = *reinterpret_cast<const bf16x8*>(&As[(wr + i * 16 + lr) * 32 + lk]);
            bfr[i] = *reinterpret_cast<const bf16x8*>(&Bs[(wc + i * 16 + lr) * 32 + lk]);
        }
#pragma unroll
        for (int mi = 0; mi < 4; ++mi)
#pragma unroll
            for (int ni = 0; ni < 4; ++ni)
                acc[mi][ni] = __builtin_amdgcn_mfma_f32_16x16x32_bf16(af[mi], bfr[ni], acc[mi][ni], 0, 0, 0);
    }

#pragma unroll
    for (int mi = 0; mi < 4; ++mi)
#pragma unroll
        for (int ni = 0; ni < 4; ++ni)
#pragma unroll
            for (int j = 0; j < 4; ++j) {
                int r = row0 + wr + mi * 16 + cr + j;
                int c = col0 + wc + ni * 16 + cc;
                C[(size_t)r * F3 + c] = f2b(acc[mi][ni][j]);
            }
}

// ===== per-32-row-tile attention compute (r7-verified core, one tile per wave) =====
static __device__ __forceinline__ void attn_tile_compute(
    const bf16x8 (&qfr)[2][2], const int (&qmv)[2],
    float (&mrow)[2], float (&lsum)[2], f32x4 (&oacc)[4][2],
    const bf16x8 (&ka)[4][2], const bf16x8 (&va)[4][2],
    const int (&km)[4][4],
    int wq0, int m0, int causal,
    u16 (*Psw)[KPAD], int g, int lq)
{
    const f32x4 fzero = {0.f, 0.f, 0.f, 0.f};
    // S^T = K Q^T : lane holds q = lq, k = kf*16 + g*4 + r
    f32x4 sacc[4][2];
#pragma unroll
    for (int kf = 0; kf < 4; ++kf)
#pragma unroll
        for (int qf = 0; qf < 2; ++qf) sacc[kf][qf] = fzero;
#pragma unroll
    for (int kf = 0; kf < 4; ++kf)
#pragma unroll
        for (int qf = 0; qf < 2; ++qf) {
            sacc[kf][qf] = __builtin_amdgcn_mfma_f32_16x16x32_bf16(ka[kf][0], qfr[qf][0], sacc[kf][qf], 0, 0, 0);
            sacc[kf][qf] = __builtin_amdgcn_mfma_f32_16x16x32_bf16(ka[kf][1], qfr[qf][1], sacc[kf][qf], 0, 0, 0);
        }

#pragma unroll
    for (int qf = 0; qf < 2; ++qf) {
        const int qg = wq0 + qf * 16 + lq;
        const bool qok = (qmv[qf] != 0);
        float s[4][4];
        float mx = -1e30f;
#pragma unroll
        for (int kf = 0; kf < 4; ++kf)
#pragma unroll
            for (int r = 0; r < 4; ++r) {
                const int kg = m0 + kf * 16 + g * 4 + r;
                float sv = sacc[kf][qf][r] * 0.125f;   // 1/sqrt(64)
                const bool ok = qok && (km[kf][r] != 0) && (!causal || kg <= qg);
                sv = ok ? sv : -1e30f;
                s[kf][r] = sv;
                mx = fmaxf(mx, sv);
            }
        mx = fmaxf(mx, __shfl_xor(mx, 16));
        mx = fmaxf(mx, __shfl_xor(mx, 32));
        const float mnew = fmaxf(mrow[qf], mx);
        const float scale = __expf(mrow[qf] - mnew);
        float rs = 0.f;
#pragma unroll
        for (int kf = 0; kf < 4; ++kf)
#pragma unroll
            for (int r = 0; r < 4; ++r) {
                const float pv = (s[kf][r] > -1e29f) ? __expf(s[kf][r] - mnew) : 0.f;
                s[kf][r] = pv;
                rs += pv;
            }
        rs += __shfl_xor(rs, 16);
        rs += __shfl_xor(rs, 32);
        lsum[qf] = lsum[qf] * scale + rs;
        mrow[qf] = mnew;
#pragma unroll
        for (int df = 0; df < 4; ++df) oacc[df][qf] *= scale;
#pragma unroll
        for (int kf = 0; kf < 4; ++kf)
#pragma unroll
            for (int r = 0; r < 4; ++r)
                Psw[qf * 16 + lq][kf * 16 + g * 4 + r] = f2b(s[kf][r]);
    }

    // O^T += V^T P^T (Psw wave-local)
    bf16x8 pb[2][2];
#pragma unroll
    for (int qf = 0; qf < 2; ++qf)
#pragma unroll
        for (int kc = 0; kc < 2; ++kc)
            pb[qf][kc] = *reinterpret_cast<const bf16x8*>(&Psw[qf * 16 + lq][kc * 32 + g * 8]);
#pragma unroll
    for (int df = 0; df < 4; ++df)
#pragma unroll
        for (int qf = 0; qf < 2; ++qf) {
            oacc[df][qf] = __builtin_amdgcn_mfma_f32_16x16x32_bf16(va[df][0], pb[qf][0], oacc[df][qf], 0, 0, 0);
            oacc[df][qf] = __builtin_amdgcn_mfma_f32_16x16x32_bf16(va[df][1], pb[qf][1], oacc[df][qf], 0, 0, 0);
        }
}

// ===== MFMA flash attention: 8-wave blocks, waves 0-3 -> tile A, waves 4-7 -> tile B =====
// Block = (b, h, pair p in 0..7): tiles (p*128, (15-p)*128). 512 threads. Output f32.
// Grid 512 blocks x 8 waves = 16 waves/CU (fixes the 2-block/CU occupancy cap of r7).
__global__ __launch_bounds__(512, 4) void attn_kernel(const u16* __restrict__ qkv,
                                                      const int* __restrict__ key_mask,
                                                      const int* __restrict__ query_mask,
                                                      const int* __restrict__ causal_p,
                                                      float* __restrict__ out) {
    const int bh = blockIdx.x;
    const int p = blockIdx.y;           // 0..7
    const int b = bh >> 4;
    const int h = bh & 15;
    const int t = threadIdx.x;
    const int lane = t & 63;
    const int wave = t >> 6;            // 0..7
    const int wtile = wave >> 2;        // 0 = tile A, 1 = tile B
    const int wsub = wave & 3;
    const int g = lane >> 4;
    const int lq = lane & 15;
    const int causal = causal_p[0];

    __shared__ u16 Ks[64][KPAD];
    __shared__ u16 Vt[64][KPAD];
    __shared__ u16 Ps[8][32][KPAD];

    const int q0 = (wtile ? (15 - p) : p) * 128;
    const int wq0 = q0 + wsub * 32;

    const f32x4 fzero = {0.f, 0.f, 0.f, 0.f};

    bf16x8 qfr[2][2];
#pragma unroll
    for (int qf = 0; qf < 2; ++qf)
#pragma unroll
        for (int ks = 0; ks < 2; ++ks)
            qfr[qf][ks] = *reinterpret_cast<const bf16x8*>(
                qkv + (size_t)(b * Nseq + wq0 + qf * 16 + lq) * F3 + h * HD + ks * 32 + g * 8);

    int qmv[2];
    float mrow[2], lsum[2];
    f32x4 oacc[4][2];
#pragma unroll
    for (int qf = 0; qf < 2; ++qf) {
        qmv[qf] = query_mask[b * Nseq + wq0 + qf * 16 + lq];
        mrow[qf] = -1e30f; lsum[qf] = 0.f;
    }
#pragma unroll
    for (int df = 0; df < 4; ++df)
#pragma unroll
        for (int qf = 0; qf < 2; ++qf) oacc[df][qf] = fzero;

    const int kvend = causal ? (q0 + 128) : Nseq;                       // this wave's range
    const int kvendMax = causal ? ((15 - p) * 128 + 128) : Nseq;        // loop bound (tile B)

    // staging geometry (512 threads): K row = t>>3, 8 cols; V: wave stages d rows [8w,8w+8), m = lane
    const int srK = t >> 3;            // 0..63
    const int scK = (t & 7) * 8;       // 0..56

    // prologue: load K/V for m0 = 0
    bf16x8 kr, vr;
    {
        kr = *reinterpret_cast<const bf16x8*>(
            qkv + (size_t)(b * Nseq + srK) * F3 + DIMc + h * HD + scK);
        vr = *reinterpret_cast<const bf16x8*>(
            qkv + (size_t)(b * Nseq + lane) * F3 + 2 * DIMc + h * HD + wave * 8);
    }

    for (int m0 = 0; m0 < kvendMax; m0 += 64) {
        // ---- write staged regs -> LDS ----
        *reinterpret_cast<bf16x8*>(&Ks[srK][scK]) = kr;
#pragma unroll
        for (int e = 0; e < 8; ++e)
            Vt[wave * 8 + e][lane] = (u16)vr[e];
        __syncthreads();

        // ---- prefetch next tile into registers (drains under compute) ----
        if (m0 + 64 < kvendMax) {
            kr = *reinterpret_cast<const bf16x8*>(
                qkv + (size_t)(b * Nseq + m0 + 64 + srK) * F3 + DIMc + h * HD + scK);
            vr = *reinterpret_cast<const bf16x8*>(
                qkv + (size_t)(b * Nseq + m0 + 64 + lane) * F3 + 2 * DIMc + h * HD + wave * 8);
        }

        // ---- compute (wave-uniform skip once past this tile's causal range) ----
        if (m0 < kvend) {
            int km[4][4];
#pragma unroll
            for (int kf = 0; kf < 4; ++kf) {
                int4 k4 = *reinterpret_cast<const int4*>(key_mask + b * Nseq + m0 + kf * 16 + g * 4);
                km[kf][0] = k4.x; km[kf][1] = k4.y; km[kf][2] = k4.z; km[kf][3] = k4.w;
            }
            bf16x8 ka[4][2], va[4][2];
#pragma unroll
            for (int kf = 0; kf < 4; ++kf)
#pragma unroll
                for (int ks = 0; ks < 2; ++ks)
                    ka[kf][ks] = *reinterpret_cast<const bf16x8*>(&Ks[kf * 16 + lq][ks * 32 + g * 8]);
#pragma unroll
            for (int df = 0; df < 4; ++df)
#pragma unroll
                for (int kc = 0; kc < 2; ++kc)
                    va[df][kc] = *reinterpret_cast<const bf16x8*>(&Vt[df * 16 + lq][kc * 32 + g * 8]);

            attn_tile_compute(qfr, qmv, mrow, lsum, oacc, ka, va, km, wq0, m0, causal,
                              Ps[wave], g, lq);
        }
        __syncthreads();
    }

    // ---- epilogue: normalize; fully-masked rows -> 0 ----
#pragma unroll
    for (int qf = 0; qf < 2; ++qf) {
        const float inv = (mrow[qf] > -1e29f && lsum[qf] > 0.f) ? 1.f / lsum[qf] : 0.f;
        const size_t rowoff = (size_t)(b * Nseq + wq0 + qf * 16 + lq) * DIMc + h * HD;
#pragma unroll
        for (int df = 0; df < 4; ++df)
#pragma unroll
            for (int r = 0; r < 4; ++r)
                out[rowoff + df * 16 + g * 4 + r] = oacc[df][qf][r] * inv;
    }
}

extern "C" void kernel_launch(void* const* d_in, const int* in_sizes, int n_in,
                              void* d_out, int out_size, void* d_ws, size_t ws_size,
                              hipStream_t stream) {
    const float* x = (const float*)d_in[0];       // [4,2048,1024] f32
    const float* W = (const float*)d_in[1];       // [3072,1024] f32

    char* ws = (char*)d_ws;
    int* km_n = (int*)(ws);
    int* qm_n = (int*)(ws + 32 * 1024);
    int* ca_n = (int*)(ws + 64 * 1024);
    u16* qkv  = (u16*)(ws + (size_t)1024 * 1024);             // 48 MiB
    u16* xb   = (u16*)(ws + (size_t)49 * 1024 * 1024);        // 16 MiB
    u16* wb   = (u16*)(ws + (size_t)65 * 1024 * 1024);        //  6 MiB

    const int nm = Bdim * Nseq;
    norm_mask_kernel<<<(nm + 255) / 256, 256, 0, stream>>>(d_in[2], nm, km_n);
    norm_mask_kernel<<<(nm + 255) / 256, 256, 0, stream>>>(d_in[3], nm, qm_n);
    norm_mask_kernel<<<1, 256, 0, stream>>>(d_in[4], 1, ca_n);

    const int nx4 = (Mrows * DIMc) / 4;
    const int nw4 = (F3 * DIMc) / 4;
    cast_f32_bf16_kernel<<<(nx4 + 255) / 256, 256, 0, stream>>>(x, xb, nx4);
    cast_f32_bf16_kernel<<<(nw4 + 255) / 256, 256, 0, stream>>>(W, wb, nw4);

    qkv_gemm_kernel<<<dim3(Mrows / 128, F3 / 128), 256, 0, stream>>>(xb, wb, qkv);

    attn_kernel<<<dim3(Bdim * NH, 8), 512, 0, stream>>>(qkv, km_n, qm_n, ca_n,
                                                        (float*)d_out);
}

// Round 13
// 267.700 us; speedup vs baseline: 1.0162x; 1.0072x over previous
//
#include <hip/hip_runtime.h>
#include <hip/hip_bf16.h>

typedef unsigned short u16;
typedef __attribute__((ext_vector_type(8))) short bf16x8;   // 8 bf16 (4 VGPRs)
typedef __attribute__((ext_vector_type(4))) float f32x4;

#define Bdim 4
#define Nseq 2048
#define DIMc 1024
#define NH   16
#define HD   64
#define F3   3072   // 3*NH*HD
#define Mrows 8192  // Bdim*Nseq

#define KPAD 68     // LDS row stride in u16: 136 B -> ~zero bank conflicts (r10/r11 verified)

typedef const __attribute__((address_space(1))) unsigned int gl_u32;
typedef __attribute__((address_space(3))) unsigned int lds_u32;

// 2^x via v_exp_f32 (NOT __exp2f: that name collides with glibc macros -> compile fail, r12)
static __device__ __forceinline__ float exp2_fast(float x) {
    return __builtin_amdgcn_exp2f(x);
}

// f32 -> bf16 RNE
static __device__ __forceinline__ u16 f2b(float f) {
    union { float f; unsigned u; } v; v.f = f;
    unsigned r = v.u + 0x7fffu + ((v.u >> 16) & 1u);
    return (u16)(r >> 16);
}

// pack 2 f32 -> 2 bf16 in one dword (RTNE), gfx950 has no builtin (guide T12)
static __device__ __forceinline__ unsigned cvt_pk_bf16(float lo, float hi) {
    unsigned r;
    asm("v_cvt_pk_bf16_f32 %0, %1, %2" : "=v"(r) : "v"(lo), "v"(hi));
    return r;
}

__global__ __launch_bounds__(256) void cast_f32_bf16_kernel(const float* __restrict__ in,
                                                            u16* __restrict__ out, int n4) {
    int i = blockIdx.x * 256 + threadIdx.x;
    if (i >= n4) return;
    float4 v = reinterpret_cast<const float4*>(in)[i];
    ushort4 o;
    o.x = f2b(v.x); o.y = f2b(v.y); o.z = f2b(v.z); o.w = f2b(v.w);
    reinterpret_cast<ushort4*>(out)[i] = o;
}

// Normalize a 0/1 mask buffer of unknown dtype (int32 / float32 / uint8) to int32.
__global__ __launch_bounds__(256) void norm_mask_kernel(const void* __restrict__ raw, int n,
                                                        int* __restrict__ outm) {
    const unsigned* as_u = (const unsigned*)raw;
    const float* as_f = (const float*)raw;
    const unsigned char* as_b = (const unsigned char*)raw;
    int ns = n < 512 ? n : 512;
    bool ok_i = true, ok_f = true;
    for (int i = 0; i < ns; ++i) {
        unsigned v = as_u[i];
        ok_i &= (v <= 1u);
        ok_f &= (v == 0u) || (v == 0x3f800000u);
    }
    const int mode = ok_i ? 0 : (ok_f ? 1 : 2);
    int i = blockIdx.x * 256 + threadIdx.x;
    if (i < n) {
        int v;
        if (mode == 0) v = (int)as_u[i];
        else if (mode == 1) v = (as_f[i] != 0.f) ? 1 : 0;
        else v = (int)as_b[i];
        outm[i] = (v != 0) ? 1 : 0;
    }
}

// ===== MFMA QKV GEMM, m97-style: global_load_lds w16, linear LDS, BK=32 =====
__global__ __launch_bounds__(256, 2) void qkv_gemm_kernel(const u16* __restrict__ A,
                                                          const u16* __restrict__ Bw,
                                                          u16* __restrict__ C) {
    __shared__ u16 As[128 * 32];
    __shared__ u16 Bs[128 * 32];
    const int t = threadIdx.x;
    const int lane = t & 63;
    const int wave = t >> 6;
    const int wr = (wave >> 1) * 64;
    const int wc = (wave & 1) * 64;
    const int row0 = blockIdx.x * 128;
    const int col0 = blockIdx.y * 128;

    const int lr = lane & 15;
    const int lk = (lane >> 4) * 8;
    const int cr = (lane >> 4) * 4;
    const int cc = lane & 15;

    const f32x4 fzero = {0.f, 0.f, 0.f, 0.f};
    f32x4 acc[4][4];
#pragma unroll
    for (int i = 0; i < 4; ++i)
#pragma unroll
        for (int j = 0; j < 4; ++j) acc[i][j] = fzero;

    const int strow = wave * 16 + (lane >> 2);
    const int stcol = (lane & 3) * 8;

    for (int k0 = 0; k0 < DIMc; k0 += 32) {
        __syncthreads();
#pragma unroll
        for (int issue = 0; issue < 2; ++issue) {
            const int r = issue * 64 + strow;
            __builtin_amdgcn_global_load_lds(
                (gl_u32*)(A + (size_t)(row0 + r) * DIMc + k0 + stcol),
                (lds_u32*)(As + (size_t)(issue * 64 + wave * 16) * 32), 16, 0, 0);
            __builtin_amdgcn_global_load_lds(
                (gl_u32*)(Bw + (size_t)(col0 + r) * DIMc + k0 + stcol),
                (lds_u32*)(Bs + (size_t)(issue * 64 + wave * 16) * 32), 16, 0, 0);
        }
        __syncthreads();

        bf16x8 af[4], bfr[4];
#pragma unroll
        for (int i = 0; i < 4; ++i) {
            af[i]  = *reinterpret_cast<const bf16x8*>(&As[(wr + i * 16 + lr) * 32 + lk]);
            bfr[i] = *reinterpret_cast<const bf16x8*>(&Bs[(wc + i * 16 + lr) * 32 + lk]);
        }
#pragma unroll
        for (int mi = 0; mi < 4; ++mi)
#pragma unroll
            for (int ni = 0; ni < 4; ++ni)
                acc[mi][ni] = __builtin_amdgcn_mfma_f32_16x16x32_bf16(af[mi], bfr[ni], acc[mi][ni], 0, 0, 0);
    }

#pragma unroll
    for (int mi = 0; mi < 4; ++mi)
#pragma unroll
        for (int ni = 0; ni < 4; ++ni)
#pragma unroll
            for (int j = 0; j < 4; ++j) {
                int r = row0 + wr + mi * 16 + cr + j;
                int c = col0 + wc + ni * 16 + cc;
                C[(size_t)r * F3 + c] = f2b(acc[mi][ni][j]);
            }
}

// ===== per-32-row-tile attention compute: fmaf-bias mask, exp2 softmax, cvt_pk P-stores =====
static __device__ __forceinline__ void attn_unit(
    const bf16x8 (&qfr)[2][2],
    float (&mrow)[2], float (&lsum)[2], f32x4 (&oacc)[4][2],
    const bf16x8 (&ka)[4][2], const bf16x8 (&va)[4][2],
    const float (&fb)[4][4],
    int wq0, int m0, bool nc,
    u16 (*Psw)[KPAD], int g, int lq)
{
    const f32x4 fzero = {0.f, 0.f, 0.f, 0.f};
    const float c2 = 0.18033688011112042f;   // 0.125 * log2(e): exp2 domain
    // S^T = K Q^T : lane holds q = lq, k = kf*16 + g*4 + r
    f32x4 sacc[4][2];
#pragma unroll
    for (int kf = 0; kf < 4; ++kf)
#pragma unroll
        for (int qf = 0; qf < 2; ++qf) sacc[kf][qf] = fzero;
#pragma unroll
    for (int kf = 0; kf < 4; ++kf)
#pragma unroll
        for (int qf = 0; qf < 2; ++qf) {
            sacc[kf][qf] = __builtin_amdgcn_mfma_f32_16x16x32_bf16(ka[kf][0], qfr[qf][0], sacc[kf][qf], 0, 0, 0);
            sacc[kf][qf] = __builtin_amdgcn_mfma_f32_16x16x32_bf16(ka[kf][1], qfr[qf][1], sacc[kf][qf], 0, 0, 0);
        }

#pragma unroll
    for (int qf = 0; qf < 2; ++qf) {
        const int qg = wq0 + qf * 16 + lq;
        float sv[4][4];
#pragma unroll
        for (int kf = 0; kf < 4; ++kf)
#pragma unroll
            for (int r = 0; r < 4; ++r)
                sv[kf][r] = fmaf(sacc[kf][qf][r], c2, fb[kf][r]);   // scale + key-mask bias
        if (nc) {   // wave-uniform: only the diagonal k-tile
#pragma unroll
            for (int kf = 0; kf < 4; ++kf)
#pragma unroll
                for (int r = 0; r < 4; ++r) {
                    const int kg = m0 + kf * 16 + g * 4 + r;
                    sv[kf][r] = (kg <= qg) ? sv[kf][r] : -1e30f;
                }
        }
        float mx = -1e30f;
#pragma unroll
        for (int kf = 0; kf < 4; ++kf)
#pragma unroll
            for (int r = 0; r < 4; ++r) mx = fmaxf(mx, sv[kf][r]);
        mx = fmaxf(mx, __shfl_xor(mx, 16));
        mx = fmaxf(mx, __shfl_xor(mx, 32));
        const float mnew = fmaxf(mrow[qf], mx);
        const float scale = exp2_fast(mrow[qf] - mnew);
        float rs = 0.f;
#pragma unroll
        for (int kf = 0; kf < 4; ++kf)
#pragma unroll
            for (int r = 0; r < 4; ++r) {
                const float pv = exp2_fast(sv[kf][r] - mnew);   // masked: underflows to 0
                sv[kf][r] = pv;
                rs += pv;
            }
        rs += __shfl_xor(rs, 16);
        rs += __shfl_xor(rs, 32);
        lsum[qf] = lsum[qf] * scale + rs;
        mrow[qf] = mnew;
#pragma unroll
        for (int df = 0; df < 4; ++df) oacc[df][qf] *= scale;
        // P -> LDS: 2 cvt_pk + 1 b64 store per kf (was 4 f2b + 4 b16 stores)
#pragma unroll
        for (int kf = 0; kf < 4; ++kf) {
            uint2 w;
            w.x = cvt_pk_bf16(sv[kf][0], sv[kf][1]);
            w.y = cvt_pk_bf16(sv[kf][2], sv[kf][3]);
            *reinterpret_cast<uint2*>(&Psw[qf * 16 + lq][kf * 16 + g * 4]) = w;
        }
    }

    // O^T += V^T P^T (Psw wave-local)
    bf16x8 pb[2][2];
#pragma unroll
    for (int qf = 0; qf < 2; ++qf)
#pragma unroll
        for (int kc = 0; kc < 2; ++kc)
            pb[qf][kc] = *reinterpret_cast<const bf16x8*>(&Psw[qf * 16 + lq][kc * 32 + g * 8]);
#pragma unroll
    for (int df = 0; df < 4; ++df)
#pragma unroll
        for (int qf = 0; qf < 2; ++qf) {
            oacc[df][qf] = __builtin_amdgcn_mfma_f32_16x16x32_bf16(va[df][0], pb[qf][0], oacc[df][qf], 0, 0, 0);
            oacc[df][qf] = __builtin_amdgcn_mfma_f32_16x16x32_bf16(va[df][1], pb[qf][1], oacc[df][qf], 0, 0, 0);
        }
}

// ===== MFMA flash attention: paired 128-row q-tiles (p, 15-p), r7 skeleton =====
__global__ __launch_bounds__(256, 2) void attn_kernel(const u16* __restrict__ qkv,
                                                      const int* __restrict__ key_mask,
                                                      const int* __restrict__ query_mask,
                                                      const int* __restrict__ causal_p,
                                                      float* __restrict__ out) {
    const int bh = blockIdx.x;
    const int p = blockIdx.y;           // 0..7
    const int b = bh >> 4;
    const int h = bh & 15;
    const int t = threadIdx.x;
    const int lane = t & 63;
    const int wave = t >> 6;
    const int g = lane >> 4;
    const int lq = lane & 15;
    const int causal = causal_p[0];

    __shared__ u16 Ks[64][KPAD];
    __shared__ u16 Vt[64][KPAD];
    __shared__ u16 Ps[4][32][KPAD];

    const int q0A = p * 128;
    const int q0B = (15 - p) * 128;
    const int wq0A = q0A + wave * 32;
    const int wq0B = q0B + wave * 32;

    const f32x4 fzero = {0.f, 0.f, 0.f, 0.f};

    bf16x8 qfrA[2][2], qfrB[2][2];
#pragma unroll
    for (int qf = 0; qf < 2; ++qf)
#pragma unroll
        for (int ks = 0; ks < 2; ++ks) {
            qfrA[qf][ks] = *reinterpret_cast<const bf16x8*>(
                qkv + (size_t)(b * Nseq + wq0A + qf * 16 + lq) * F3 + h * HD + ks * 32 + g * 8);
            qfrB[qf][ks] = *reinterpret_cast<const bf16x8*>(
                qkv + (size_t)(b * Nseq + wq0B + qf * 16 + lq) * F3 + h * HD + ks * 32 + g * 8);
        }

    int qmA[2], qmB[2];
    float mrowA[2], lsumA[2], mrowB[2], lsumB[2];
    f32x4 oaccA[4][2], oaccB[4][2];
#pragma unroll
    for (int qf = 0; qf < 2; ++qf) {
        qmA[qf] = query_mask[b * Nseq + wq0A + qf * 16 + lq];
        qmB[qf] = query_mask[b * Nseq + wq0B + qf * 16 + lq];
        mrowA[qf] = -1e30f; lsumA[qf] = 0.f;
        mrowB[qf] = -1e30f; lsumB[qf] = 0.f;
    }
#pragma unroll
    for (int df = 0; df < 4; ++df)
#pragma unroll
        for (int qf = 0; qf < 2; ++qf) { oaccA[df][qf] = fzero; oaccB[df][qf] = fzero; }

    // per-wave compute ranges (rows [wq0, wq0+32) need k <= wq0+31)
    const int kvA = causal ? (wq0A + 32) : Nseq;
    const int kvB = causal ? (wq0B + 32) : Nseq;
    const int kvendMax = causal ? (q0B + 128) : Nseq;   // staging bound (block-uniform)

    const int sr = t >> 2;
    const int sc = (t & 3) * 8;

    // prologue: load K/V for m0 = 0
    bf16x8 kr0, kr1, vr0, vr1;
    {
        const u16* krow = qkv + (size_t)(b * Nseq + sr) * F3 + DIMc + h * HD;
        kr0 = *reinterpret_cast<const bf16x8*>(krow + sc);
        kr1 = *reinterpret_cast<const bf16x8*>(krow + sc + 32);
        const u16* vrow = qkv + (size_t)(b * Nseq + lane) * F3 + 2 * DIMc + h * HD + wave * 16;
        vr0 = *reinterpret_cast<const bf16x8*>(vrow);
        vr1 = *reinterpret_cast<const bf16x8*>(vrow + 8);
    }

    for (int m0 = 0; m0 < kvendMax; m0 += 64) {
        // ---- write staged regs -> LDS ----
        *reinterpret_cast<bf16x8*>(&Ks[sr][sc])      = kr0;
        *reinterpret_cast<bf16x8*>(&Ks[sr][sc + 32]) = kr1;
#pragma unroll
        for (int e = 0; e < 8; ++e) {
            Vt[wave * 16 + e][lane]     = (u16)vr0[e];
            Vt[wave * 16 + 8 + e][lane] = (u16)vr1[e];
        }
        __syncthreads();

        // ---- prefetch next tile into registers ----
        if (m0 + 64 < kvendMax) {
            const u16* krow = qkv + (size_t)(b * Nseq + m0 + 64 + sr) * F3 + DIMc + h * HD;
            kr0 = *reinterpret_cast<const bf16x8*>(krow + sc);
            kr1 = *reinterpret_cast<const bf16x8*>(krow + sc + 32);
            const u16* vrow = qkv + (size_t)(b * Nseq + m0 + 64 + lane) * F3 + 2 * DIMc + h * HD + wave * 16;
            vr0 = *reinterpret_cast<const bf16x8*>(vrow);
            vr1 = *reinterpret_cast<const bf16x8*>(vrow + 8);
        }

        // ---- shared per-iteration state: key-mask bias + K/V fragments ----
        float fb[4][4];
#pragma unroll
        for (int kf = 0; kf < 4; ++kf) {
            int4 k4 = *reinterpret_cast<const int4*>(key_mask + b * Nseq + m0 + kf * 16 + g * 4);
            fb[kf][0] = k4.x ? 0.f : -1e30f;
            fb[kf][1] = k4.y ? 0.f : -1e30f;
            fb[kf][2] = k4.z ? 0.f : -1e30f;
            fb[kf][3] = k4.w ? 0.f : -1e30f;
        }
        bf16x8 ka[4][2], va[4][2];
#pragma unroll
        for (int kf = 0; kf < 4; ++kf)
#pragma unroll
            for (int ks = 0; ks < 2; ++ks)
                ka[kf][ks] = *reinterpret_cast<const bf16x8*>(&Ks[kf * 16 + lq][ks * 32 + g * 8]);
#pragma unroll
        for (int df = 0; df < 4; ++df)
#pragma unroll
            for (int kc = 0; kc < 2; ++kc)
                va[df][kc] = *reinterpret_cast<const bf16x8*>(&Vt[df * 16 + lq][kc * 32 + g * 8]);

        // ---- tile B then tile A (per-wave ranges; causal select only on diagonal) ----
        if (m0 < kvB)
            attn_unit(qfrB, mrowB, lsumB, oaccB, ka, va, fb, wq0B, m0,
                      causal && (m0 + 64 > wq0B), Ps[wave], g, lq);
        if (m0 < kvA)
            attn_unit(qfrA, mrowA, lsumA, oaccA, ka, va, fb, wq0A, m0,
                      causal && (m0 + 64 > wq0A), Ps[wave], g, lq);
        __syncthreads();
    }

    // ---- epilogue: normalize; query-masked / fully-masked rows -> 0 ----
#pragma unroll
    for (int qf = 0; qf < 2; ++qf) {
        const float invA = (qmA[qf] != 0 && mrowA[qf] > -1e29f && lsumA[qf] > 0.f) ? 1.f / lsumA[qf] : 0.f;
        const float invB = (qmB[qf] != 0 && mrowB[qf] > -1e29f && lsumB[qf] > 0.f) ? 1.f / lsumB[qf] : 0.f;
        const size_t rowA = (size_t)(b * Nseq + wq0A + qf * 16 + lq) * DIMc + h * HD;
        const size_t rowB = (size_t)(b * Nseq + wq0B + qf * 16 + lq) * DIMc + h * HD;
#pragma unroll
        for (int df = 0; df < 4; ++df)
#pragma unroll
            for (int r = 0; r < 4; ++r) {
                out[rowA + df * 16 + g * 4 + r] = oaccA[df][qf][r] * invA;
                out[rowB + df * 16 + g * 4 + r] = oaccB[df][qf][r] * invB;
            }
    }
}

extern "C" void kernel_launch(void* const* d_in, const int* in_sizes, int n_in,
                              void* d_out, int out_size, void* d_ws, size_t ws_size,
                              hipStream_t stream) {
    const float* x = (const float*)d_in[0];       // [4,2048,1024] f32
    const float* W = (const float*)d_in[1];       // [3072,1024] f32

    char* ws = (char*)d_ws;
    int* km_n = (int*)(ws);
    int* qm_n = (int*)(ws + 32 * 1024);
    int* ca_n = (int*)(ws + 64 * 1024);
    u16* qkv  = (u16*)(ws + (size_t)1024 * 1024);             // 48 MiB
    u16* xb   = (u16*)(ws + (size_t)49 * 1024 * 1024);        // 16 MiB
    u16* wb   = (u16*)(ws + (size_t)65 * 1024 * 1024);        //  6 MiB

    const int nm = Bdim * Nseq;
    norm_mask_kernel<<<(nm + 255) / 256, 256, 0, stream>>>(d_in[2], nm, km_n);
    norm_mask_kernel<<<(nm + 255) / 256, 256, 0, stream>>>(d_in[3], nm, qm_n);
    norm_mask_kernel<<<1, 256, 0, stream>>>(d_in[4], 1, ca_n);

    const int nx4 = (Mrows * DIMc) / 4;
    const int nw4 = (F3 * DIMc) / 4;
    cast_f32_bf16_kernel<<<(nx4 + 255) / 256, 256, 0, stream>>>(x, xb, nx4);
    cast_f32_bf16_kernel<<<(nw4 + 255) / 256, 256, 0, stream>>>(W, wb, nw4);

    qkv_gemm_kernel<<<dim3(Mrows / 128, F3 / 128), 256, 0, stream>>>(xb, wb, qkv);

    attn_kernel<<<dim3(Bdim * NH, 8), 256, 0, stream>>>(qkv, km_n, qm_n, ca_n,
                                                        (float*)d_out);
}

// Round 14
// 264.069 us; speedup vs baseline: 1.0302x; 1.0138x over previous
//
#include <hip/hip_runtime.h>
#include <hip/hip_bf16.h>

typedef unsigned short u16;
typedef __attribute__((ext_vector_type(8))) short bf16x8;   // 8 bf16 (4 VGPRs)
typedef __attribute__((ext_vector_type(4))) float f32x4;

#define Bdim 4
#define Nseq 2048
#define DIMc 1024
#define NH   16
#define HD   64
#define F3   3072   // 3*NH*HD
#define Mrows 8192  // Bdim*Nseq

#define KPAD 68     // LDS row stride in u16: 136 B -> ~zero bank conflicts (r10/r11 verified)

typedef const __attribute__((address_space(1))) unsigned int gl_u32;
typedef __attribute__((address_space(3))) unsigned int lds_u32;

// f32 -> bf16 RNE
static __device__ __forceinline__ u16 f2b(float f) {
    union { float f; unsigned u; } v; v.f = f;
    unsigned r = v.u + 0x7fffu + ((v.u >> 16) & 1u);
    return (u16)(r >> 16);
}

__global__ __launch_bounds__(256) void cast_f32_bf16_kernel(const float* __restrict__ in,
                                                            u16* __restrict__ out, int n4) {
    int i = blockIdx.x * 256 + threadIdx.x;
    if (i >= n4) return;
    float4 v = reinterpret_cast<const float4*>(in)[i];
    ushort4 o;
    o.x = f2b(v.x); o.y = f2b(v.y); o.z = f2b(v.z); o.w = f2b(v.w);
    reinterpret_cast<ushort4*>(out)[i] = o;
}

// Normalize a 0/1 mask buffer of unknown dtype (int32 / float32 / uint8) to int32.
__global__ __launch_bounds__(256) void norm_mask_kernel(const void* __restrict__ raw, int n,
                                                        int* __restrict__ outm) {
    const unsigned* as_u = (const unsigned*)raw;
    const float* as_f = (const float*)raw;
    const unsigned char* as_b = (const unsigned char*)raw;
    int ns = n < 512 ? n : 512;
    bool ok_i = true, ok_f = true;
    for (int i = 0; i < ns; ++i) {
        unsigned v = as_u[i];
        ok_i &= (v <= 1u);
        ok_f &= (v == 0u) || (v == 0x3f800000u);
    }
    const int mode = ok_i ? 0 : (ok_f ? 1 : 2);
    int i = blockIdx.x * 256 + threadIdx.x;
    if (i < n) {
        int v;
        if (mode == 0) v = (int)as_u[i];
        else if (mode == 1) v = (as_f[i] != 0.f) ? 1 : 0;
        else v = (int)as_b[i];
        outm[i] = (v != 0) ? 1 : 0;
    }
}

// ===== MFMA QKV GEMM, m97-style: global_load_lds w16, linear LDS, BK=32 =====
__global__ __launch_bounds__(256, 2) void qkv_gemm_kernel(const u16* __restrict__ A,
                                                          const u16* __restrict__ Bw,
                                                          u16* __restrict__ C) {
    __shared__ u16 As[128 * 32];
    __shared__ u16 Bs[128 * 32];
    const int t = threadIdx.x;
    const int lane = t & 63;
    const int wave = t >> 6;
    const int wr = (wave >> 1) * 64;
    const int wc = (wave & 1) * 64;
    const int row0 = blockIdx.x * 128;
    const int col0 = blockIdx.y * 128;

    const int lr = lane & 15;
    const int lk = (lane >> 4) * 8;
    const int cr = (lane >> 4) * 4;
    const int cc = lane & 15;

    const f32x4 fzero = {0.f, 0.f, 0.f, 0.f};
    f32x4 acc[4][4];
#pragma unroll
    for (int i = 0; i < 4; ++i)
#pragma unroll
        for (int j = 0; j < 4; ++j) acc[i][j] = fzero;

    const int strow = wave * 16 + (lane >> 2);
    const int stcol = (lane & 3) * 8;

    for (int k0 = 0; k0 < DIMc; k0 += 32) {
        __syncthreads();
#pragma unroll
        for (int issue = 0; issue < 2; ++issue) {
            const int r = issue * 64 + strow;
            __builtin_amdgcn_global_load_lds(
                (gl_u32*)(A + (size_t)(row0 + r) * DIMc + k0 + stcol),
                (lds_u32*)(As + (size_t)(issue * 64 + wave * 16) * 32), 16, 0, 0);
            __builtin_amdgcn_global_load_lds(
                (gl_u32*)(Bw + (size_t)(col0 + r) * DIMc + k0 + stcol),
                (lds_u32*)(Bs + (size_t)(issue * 64 + wave * 16) * 32), 16, 0, 0);
        }
        __syncthreads();

        bf16x8 af[4], bfr[4];
#pragma unroll
        for (int i = 0; i < 4; ++i) {
            af[i]  = *reinterpret_cast<const bf16x8*>(&As[(wr + i * 16 + lr) * 32 + lk]);
            bfr[i] = *reinterpret_cast<const bf16x8*>(&Bs[(wc + i * 16 + lr) * 32 + lk]);
        }
#pragma unroll
        for (int mi = 0; mi < 4; ++mi)
#pragma unroll
            for (int ni = 0; ni < 4; ++ni)
                acc[mi][ni] = __builtin_amdgcn_mfma_f32_16x16x32_bf16(af[mi], bfr[ni], acc[mi][ni], 0, 0, 0);
    }

#pragma unroll
    for (int mi = 0; mi < 4; ++mi)
#pragma unroll
        for (int ni = 0; ni < 4; ++ni)
#pragma unroll
            for (int j = 0; j < 4; ++j) {
                int r = row0 + wr + mi * 16 + cr + j;
                int c = col0 + wc + ni * 16 + cc;
                C[(size_t)r * F3 + c] = f2b(acc[mi][ni][j]);
            }
}

// ===== per-32-row-tile attention compute (r7-verified softmax, bit-identical) =====
static __device__ __forceinline__ void attn_tile_compute(
    const bf16x8 (&qfr)[2][2], const int (&qmv)[2],
    float (&mrow)[2], float (&lsum)[2], f32x4 (&oacc)[4][2],
    const bf16x8 (&ka)[4][2], const bf16x8 (&va)[4][2],
    const int (&km)[4][4],
    int wq0, int m0, int causal,
    u16 (*Psw)[KPAD], int g, int lq)
{
    const f32x4 fzero = {0.f, 0.f, 0.f, 0.f};
    // S^T = K Q^T : lane holds q = lq, k = kf*16 + g*4 + r
    f32x4 sacc[4][2];
#pragma unroll
    for (int kf = 0; kf < 4; ++kf)
#pragma unroll
        for (int qf = 0; qf < 2; ++qf) sacc[kf][qf] = fzero;
#pragma unroll
    for (int kf = 0; kf < 4; ++kf)
#pragma unroll
        for (int qf = 0; qf < 2; ++qf) {
            sacc[kf][qf] = __builtin_amdgcn_mfma_f32_16x16x32_bf16(ka[kf][0], qfr[qf][0], sacc[kf][qf], 0, 0, 0);
            sacc[kf][qf] = __builtin_amdgcn_mfma_f32_16x16x32_bf16(ka[kf][1], qfr[qf][1], sacc[kf][qf], 0, 0, 0);
        }

#pragma unroll
    for (int qf = 0; qf < 2; ++qf) {
        const int qg = wq0 + qf * 16 + lq;
        const bool qok = (qmv[qf] != 0);
        float s[4][4];
        float mx = -1e30f;
#pragma unroll
        for (int kf = 0; kf < 4; ++kf)
#pragma unroll
            for (int r = 0; r < 4; ++r) {
                const int kg = m0 + kf * 16 + g * 4 + r;
                float sv = sacc[kf][qf][r] * 0.125f;   // 1/sqrt(64)
                const bool ok = qok && (km[kf][r] != 0) && (!causal || kg <= qg);
                sv = ok ? sv : -1e30f;
                s[kf][r] = sv;
                mx = fmaxf(mx, sv);
            }
        mx = fmaxf(mx, __shfl_xor(mx, 16));
        mx = fmaxf(mx, __shfl_xor(mx, 32));
        const float mnew = fmaxf(mrow[qf], mx);
        const float scale = __expf(mrow[qf] - mnew);
        float rs = 0.f;
#pragma unroll
        for (int kf = 0; kf < 4; ++kf)
#pragma unroll
            for (int r = 0; r < 4; ++r) {
                const float pv = (s[kf][r] > -1e29f) ? __expf(s[kf][r] - mnew) : 0.f;
                s[kf][r] = pv;
                rs += pv;
            }
        rs += __shfl_xor(rs, 16);
        rs += __shfl_xor(rs, 32);
        lsum[qf] = lsum[qf] * scale + rs;
        mrow[qf] = mnew;
#pragma unroll
        for (int df = 0; df < 4; ++df) oacc[df][qf] *= scale;
#pragma unroll
        for (int kf = 0; kf < 4; ++kf)
#pragma unroll
            for (int r = 0; r < 4; ++r)
                Psw[qf * 16 + lq][kf * 16 + g * 4 + r] = f2b(s[kf][r]);
    }

    // O^T += V^T P^T (Psw wave-local)
    bf16x8 pb[2][2];
#pragma unroll
    for (int qf = 0; qf < 2; ++qf)
#pragma unroll
        for (int kc = 0; kc < 2; ++kc)
            pb[qf][kc] = *reinterpret_cast<const bf16x8*>(&Psw[qf * 16 + lq][kc * 32 + g * 8]);
#pragma unroll
    for (int df = 0; df < 4; ++df)
#pragma unroll
        for (int qf = 0; qf < 2; ++qf) {
            oacc[df][qf] = __builtin_amdgcn_mfma_f32_16x16x32_bf16(va[df][0], pb[qf][0], oacc[df][qf], 0, 0, 0);
            oacc[df][qf] = __builtin_amdgcn_mfma_f32_16x16x32_bf16(va[df][1], pb[qf][1], oacc[df][qf], 0, 0, 0);
        }
}

// ===== MFMA flash attention: r7 skeleton + double-buffered K/V LDS (1 barrier/slice) =====
// Block = (b, h, pair p in 0..7). 4 waves x 32 q-rows per tile. Output f32.
__global__ __launch_bounds__(256, 2) void attn_kernel(const u16* __restrict__ qkv,
                                                      const int* __restrict__ key_mask,
                                                      const int* __restrict__ query_mask,
                                                      const int* __restrict__ causal_p,
                                                      float* __restrict__ out) {
    const int bh = blockIdx.x;
    const int p = blockIdx.y;           // 0..7
    const int b = bh >> 4;
    const int h = bh & 15;
    const int t = threadIdx.x;
    const int lane = t & 63;
    const int wave = t >> 6;
    const int g = lane >> 4;
    const int lq = lane & 15;
    const int causal = causal_p[0];

    __shared__ u16 Ks[2][64][KPAD];   // double-buffered K
    __shared__ u16 Vt[2][64][KPAD];   // double-buffered V^T
    __shared__ u16 Ps[4][32][KPAD];

    const int q0A = p * 128;
    const int q0B = (15 - p) * 128;
    const int wq0A = q0A + wave * 32;
    const int wq0B = q0B + wave * 32;

    const f32x4 fzero = {0.f, 0.f, 0.f, 0.f};

    bf16x8 qfrA[2][2], qfrB[2][2];
#pragma unroll
    for (int qf = 0; qf < 2; ++qf)
#pragma unroll
        for (int ks = 0; ks < 2; ++ks) {
            qfrA[qf][ks] = *reinterpret_cast<const bf16x8*>(
                qkv + (size_t)(b * Nseq + wq0A + qf * 16 + lq) * F3 + h * HD + ks * 32 + g * 8);
            qfrB[qf][ks] = *reinterpret_cast<const bf16x8*>(
                qkv + (size_t)(b * Nseq + wq0B + qf * 16 + lq) * F3 + h * HD + ks * 32 + g * 8);
        }

    int qmA[2], qmB[2];
    float mrowA[2], lsumA[2], mrowB[2], lsumB[2];
    f32x4 oaccA[4][2], oaccB[4][2];
#pragma unroll
    for (int qf = 0; qf < 2; ++qf) {
        qmA[qf] = query_mask[b * Nseq + wq0A + qf * 16 + lq];
        qmB[qf] = query_mask[b * Nseq + wq0B + qf * 16 + lq];
        mrowA[qf] = -1e30f; lsumA[qf] = 0.f;
        mrowB[qf] = -1e30f; lsumB[qf] = 0.f;
    }
#pragma unroll
    for (int df = 0; df < 4; ++df)
#pragma unroll
        for (int qf = 0; qf < 2; ++qf) { oaccA[df][qf] = fzero; oaccB[df][qf] = fzero; }

    // per-wave compute ranges (rows [wq0, wq0+32) need k <= wq0+31)
    const int kvA = causal ? (wq0A + 32) : Nseq;
    const int kvB = causal ? (wq0B + 32) : Nseq;
    const int kvendMax = causal ? (q0B + 128) : Nseq;   // staging bound (block-uniform)

    const int sr = t >> 2;
    const int sc = (t & 3) * 8;

    // prologue: stage slice 0 into buf 0; preload slice 1 into regs
    bf16x8 kr0, kr1, vr0, vr1;
    {
        const u16* krow = qkv + (size_t)(b * Nseq + sr) * F3 + DIMc + h * HD;
        kr0 = *reinterpret_cast<const bf16x8*>(krow + sc);
        kr1 = *reinterpret_cast<const bf16x8*>(krow + sc + 32);
        const u16* vrow = qkv + (size_t)(b * Nseq + lane) * F3 + 2 * DIMc + h * HD + wave * 16;
        vr0 = *reinterpret_cast<const bf16x8*>(vrow);
        vr1 = *reinterpret_cast<const bf16x8*>(vrow + 8);
        *reinterpret_cast<bf16x8*>(&Ks[0][sr][sc])      = kr0;
        *reinterpret_cast<bf16x8*>(&Ks[0][sr][sc + 32]) = kr1;
#pragma unroll
        for (int e = 0; e < 8; ++e) {
            Vt[0][wave * 16 + e][lane]     = (u16)vr0[e];
            Vt[0][wave * 16 + 8 + e][lane] = (u16)vr1[e];
        }
        if (64 < kvendMax) {
            const u16* krow1 = qkv + (size_t)(b * Nseq + 64 + sr) * F3 + DIMc + h * HD;
            kr0 = *reinterpret_cast<const bf16x8*>(krow1 + sc);
            kr1 = *reinterpret_cast<const bf16x8*>(krow1 + sc + 32);
            const u16* vrow1 = qkv + (size_t)(b * Nseq + 64 + lane) * F3 + 2 * DIMc + h * HD + wave * 16;
            vr0 = *reinterpret_cast<const bf16x8*>(vrow1);
            vr1 = *reinterpret_cast<const bf16x8*>(vrow1 + 8);
        }
    }

    int cur = 0;
    for (int m0 = 0; m0 < kvendMax; m0 += 64) {
        __syncthreads();   // buf[cur] writes visible; prior reads of buf[cur^1] complete

        // ---- compute from buf[cur] ----
        int km[4][4];
#pragma unroll
        for (int kf = 0; kf < 4; ++kf) {
            int4 k4 = *reinterpret_cast<const int4*>(key_mask + b * Nseq + m0 + kf * 16 + g * 4);
            km[kf][0] = k4.x; km[kf][1] = k4.y; km[kf][2] = k4.z; km[kf][3] = k4.w;
        }
        bf16x8 ka[4][2], va[4][2];
#pragma unroll
        for (int kf = 0; kf < 4; ++kf)
#pragma unroll
            for (int ks = 0; ks < 2; ++ks)
                ka[kf][ks] = *reinterpret_cast<const bf16x8*>(&Ks[cur][kf * 16 + lq][ks * 32 + g * 8]);
#pragma unroll
        for (int df = 0; df < 4; ++df)
#pragma unroll
            for (int kc = 0; kc < 2; ++kc)
                va[df][kc] = *reinterpret_cast<const bf16x8*>(&Vt[cur][df * 16 + lq][kc * 32 + g * 8]);

        if (m0 < kvB)
            attn_tile_compute(qfrB, qmB, mrowB, lsumB, oaccB, ka, va, km, wq0B, m0, causal,
                              Ps[wave], g, lq);
        if (m0 < kvA)
            attn_tile_compute(qfrA, qmA, mrowA, lsumA, oaccA, ka, va, km, wq0A, m0, causal,
                              Ps[wave], g, lq);

        // ---- write next slice (staged in regs) into buf[cur^1]; then issue next loads ----
        if (m0 + 64 < kvendMax) {
            *reinterpret_cast<bf16x8*>(&Ks[cur ^ 1][sr][sc])      = kr0;
            *reinterpret_cast<bf16x8*>(&Ks[cur ^ 1][sr][sc + 32]) = kr1;
#pragma unroll
            for (int e = 0; e < 8; ++e) {
                Vt[cur ^ 1][wave * 16 + e][lane]     = (u16)vr0[e];
                Vt[cur ^ 1][wave * 16 + 8 + e][lane] = (u16)vr1[e];
            }
            if (m0 + 128 < kvendMax) {
                const u16* krow = qkv + (size_t)(b * Nseq + m0 + 128 + sr) * F3 + DIMc + h * HD;
                kr0 = *reinterpret_cast<const bf16x8*>(krow + sc);
                kr1 = *reinterpret_cast<const bf16x8*>(krow + sc + 32);
                const u16* vrow = qkv + (size_t)(b * Nseq + m0 + 128 + lane) * F3 + 2 * DIMc + h * HD + wave * 16;
                vr0 = *reinterpret_cast<const bf16x8*>(vrow);
                vr1 = *reinterpret_cast<const bf16x8*>(vrow + 8);
            }
        }
        cur ^= 1;
    }

    // ---- epilogue: normalize; fully-masked rows -> 0 ----
#pragma unroll
    for (int qf = 0; qf < 2; ++qf) {
        const float invA = (mrowA[qf] > -1e29f && lsumA[qf] > 0.f) ? 1.f / lsumA[qf] : 0.f;
        const float invB = (mrowB[qf] > -1e29f && lsumB[qf] > 0.f) ? 1.f / lsumB[qf] : 0.f;
        const size_t rowA = (size_t)(b * Nseq + wq0A + qf * 16 + lq) * DIMc + h * HD;
        const size_t rowB = (size_t)(b * Nseq + wq0B + qf * 16 + lq) * DIMc + h * HD;
#pragma unroll
        for (int df = 0; df < 4; ++df)
#pragma unroll
            for (int r = 0; r < 4; ++r) {
                out[rowA + df * 16 + g * 4 + r] = oaccA[df][qf][r] * invA;
                out[rowB + df * 16 + g * 4 + r] = oaccB[df][qf][r] * invB;
            }
    }
}

extern "C" void kernel_launch(void* const* d_in, const int* in_sizes, int n_in,
                              void* d_out, int out_size, void* d_ws, size_t ws_size,
                              hipStream_t stream) {
    const float* x = (const float*)d_in[0];       // [4,2048,1024] f32
    const float* W = (const float*)d_in[1];       // [3072,1024] f32

    char* ws = (char*)d_ws;
    int* km_n = (int*)(ws);
    int* qm_n = (int*)(ws + 32 * 1024);
    int* ca_n = (int*)(ws + 64 * 1024);
    u16* qkv  = (u16*)(ws + (size_t)1024 * 1024);             // 48 MiB
    u16* xb   = (u16*)(ws + (size_t)49 * 1024 * 1024);        // 16 MiB
    u16* wb   = (u16*)(ws + (size_t)65 * 1024 * 1024);        //  6 MiB

    const int nm = Bdim * Nseq;
    norm_mask_kernel<<<(nm + 255) / 256, 256, 0, stream>>>(d_in[2], nm, km_n);
    norm_mask_kernel<<<(nm + 255) / 256, 256, 0, stream>>>(d_in[3], nm, qm_n);
    norm_mask_kernel<<<1, 256, 0, stream>>>(d_in[4], 1, ca_n);

    const int nx4 = (Mrows * DIMc) / 4;
    const int nw4 = (F3 * DIMc) / 4;
    cast_f32_bf16_kernel<<<(nx4 + 255) / 256, 256, 0, stream>>>(x, xb, nx4);
    cast_f32_bf16_kernel<<<(nw4 + 255) / 256, 256, 0, stream>>>(W, wb, nw4);

    qkv_gemm_kernel<<<dim3(Mrows / 128, F3 / 128), 256, 0, stream>>>(xb, wb, qkv);

    attn_kernel<<<dim3(Bdim * NH, 8), 256, 0, stream>>>(qkv, km_n, qm_n, ca_n,
                                                        (float*)d_out);
}